// Round 23
// baseline (2435.100 us; speedup 1.0000x reference)
//
#include <hip/hip_runtime.h>
#include <hip/hip_fp16.h>
#include <cmath>

#define RN 512
#define RT 1024
#define RB 64
#define SMEM_BYTES 86016   // pad -> exactly 1 block/CU (keeps XCD-rank math exact)

typedef _Float16 half2v __attribute__((ext_vector_type(2)));

__device__ __forceinline__ float fast_tanh(float x) {
    float e = __expf(2.0f * x);
    return 1.0f - 2.0f / (e + 1.0f);
}
__device__ __forceinline__ unsigned pack2(float a, float b) {   // RNE
    return (unsigned)__half_as_ushort(__float2half(a)) |
           ((unsigned)__half_as_ushort(__float2half(b)) << 16);
}
__device__ __forceinline__ unsigned pkrtz(float a, float b) {
    auto h = __builtin_amdgcn_cvt_pkrtz(a, b);
    return __builtin_bit_cast(unsigned, h);
}
__device__ __forceinline__ float dot2(unsigned wa, unsigned tb, float acc) {
    half2v a = __builtin_bit_cast(half2v, wa);
    half2v b = __builtin_bit_cast(half2v, tb);
    return __builtin_amdgcn_fdot2(a, b, acc, false);
}
template <int CTRL>
__device__ __forceinline__ float dpp_add(float x) {
    int p = __builtin_amdgcn_update_dpp(0, __float_as_int(x), CTRL, 0xf, 0xf, true);
    return x + __int_as_float(p);
}
__device__ __forceinline__ float red16(float x) {
    x = dpp_add<0xB1>(x);   // quad_perm xor1
    x = dpp_add<0x4E>(x);   // quad_perm xor2
    x = dpp_add<0x141>(x);  // row_half_mirror
    x = dpp_add<0x140>(x);  // row_mirror
    return x;
}
#define D2Q(acc, wq, tq) \
    acc = dot2((wq).x, (tq).x, acc); acc = dot2((wq).y, (tq).y, acc); \
    acc = dot2((wq).z, (tq).z, acc); acc = dot2((wq).w, (tq).w, acc);

#define PIN4(v) asm volatile("" : "+v"((v).x), "+v"((v).y), "+v"((v).z), "+v"((v).w));

// FAN-2: 2 blocks per batch (part = half of 512 rows). Per-thread W = 32 uint4
// = 128 VGPRs, register-resident (R20 pattern, doubled; cap 256 at (512,1)).
// Thread (rg=tid>>4 -> 8 rows [part*256+rg*8,+8), kc=tid&15 -> 16-k subchunk
// per 256-k half). Phase A (own half: 64 dot2, th from ownpk LDS) runs before
// the poll -> HALF the dot work is partner-independent (was 1/4). Phase B =
// ONE partner band (4 float4 + 8 pkrtz + 64 dot2). 2 arrivals/step (was 4):
// fewer skew contributors. Poll busy-spins (no s_sleep quantization).
// Protocol otherwise = R20/R22 champion: same-XCD pairs via XCC_ID rank,
// relaxed tid0 poll + barrier bcast, fp32-outH exchange (fresh addresses),
// DPP reduce, per-wave drain -> LDS arrival -> 8th wave signals.
#define DECLW(pre) uint4 pre##0_0, pre##0_1, pre##1_0, pre##1_1, pre##2_0, pre##2_1, \
    pre##3_0, pre##3_1, pre##4_0, pre##4_1, pre##5_0, pre##5_1, pre##6_0, pre##6_1, \
    pre##7_0, pre##7_1;

#define LW(pre, base, r) \
    pre##r##_0 = (base)[((r)*2 + 0) * 512]; PIN4(pre##r##_0) \
    pre##r##_1 = (base)[((r)*2 + 1) * 512]; PIN4(pre##r##_1)

#define LOADALL(pre, base) \
    LW(pre, base, 0) LW(pre, base, 1) LW(pre, base, 2) LW(pre, base, 3) \
    LW(pre, base, 4) LW(pre, base, 5) LW(pre, base, 6) LW(pre, base, 7)

#define DOTA(r) D2Q(a##r, wa##r##_0, th0) D2Q(a##r, wa##r##_1, th1)
#define DOTBq(r) D2Q(a##r, wb##r##_0, tb0) D2Q(a##r, wb##r##_1, tb1)

__global__ void __launch_bounds__(512, 1) rnn_step_kernel(
    const float* __restrict__ h0,
    const float* __restrict__ X,
    const uint4* __restrict__ Wpk,     // [2 p][2 hf][16 k][512 tid]
    const float* __restrict__ tanh0,
    float* __restrict__ outH,
    unsigned* __restrict__ ctr,
    unsigned* __restrict__ xcdctr)
{
    extern __shared__ unsigned char smem[];
    unsigned* ownpk = (unsigned*)smem;               // 128 u32: own 256 rows packed
    int*      bc    = (int*)(smem + 512);
    unsigned* lctr  = (unsigned*)(smem + 528);

    const int tid = threadIdx.x;
    if (tid == 0) {
        unsigned xcd;
        asm volatile("s_getreg_b32 %0, hwreg(HW_REG_XCC_ID)" : "=s"(xcd));
        xcd &= 7u;
        unsigned rank = __hip_atomic_fetch_add(&xcdctr[xcd], 1u,
                            __ATOMIC_RELAXED, __HIP_MEMORY_SCOPE_AGENT) & 31u;
        if (rank < 16u) {
            int slot = (int)(xcd * 16u + rank);   // 0..127
            bc[0] = slot >> 1;                    // batch 0..63
            bc[1] = slot & 1;                     // part  0..1
            bc[2] = 1;
        } else {
            bc[2] = 0;                            // surplus block: exit
        }
        *lctr = 0u;
    }
    __syncthreads();
    if (bc[2] == 0) return;                       // wave-uniform exit
    const int batch = bc[0], part = bc[1];
    const int hfp = 1 - part;                     // partner k-half

    // W fragment -> 32 named uint4 registers (own half wa*, partner half wb*)
    DECLW(wa) DECLW(wb)
    {
        const uint4* wsA = Wpk + part * 16384 + part * 8192 + tid;
        const uint4* wsB = Wpk + part * 16384 + hfp  * 8192 + tid;
        LOADALL(wa, wsA)
        LOADALL(wb, wsB)
    }

    const int rg = tid >> 4;                  // 0..31 : 8-row group
    const int kc = tid & 15;                  // 0..15 : 16-k subchunk per half
    const int row0 = part * 256 + rg * 8;

    // persistent pointers
    const float* srcB  = tanh0;
    const float* xPtr  = X    + (size_t)batch * RT * RN + row0;
    float*       oPtr  = outH + (size_t)batch * RT * RN + row0;
    const float* oBase = outH + (size_t)batch * RT * RN;

    float4 hA = {0,0,0,0}, hB = {0,0,0,0};
    float4 xvA = {0,0,0,0}, xvB = {0,0,0,0};
    if (kc == 0) {
        hA = *reinterpret_cast<const float4*>(h0 + row0);
        hB = *reinterpret_cast<const float4*>(h0 + row0 + 4);
        float t0 = tanhf(hA.x), t1 = tanhf(hA.y), t2 = tanhf(hA.z), t3 = tanhf(hA.w);
        float t4 = tanhf(hB.x), t5 = tanhf(hB.y), t6 = tanhf(hB.z), t7 = tanhf(hB.w);
        *reinterpret_cast<uint4*>(&ownpk[rg * 4]) =
            make_uint4(pack2(t0, t1), pack2(t2, t3), pack2(t4, t5), pack2(t6, t7));
        xvA = *reinterpret_cast<const float4*>(xPtr);
        xvB = *reinterpret_cast<const float4*>(xPtr + 4);
    }

    unsigned* gctr = ctr + batch * 32;        // 128B line per pair
    __syncthreads();                          // ownpk staged

    #pragma unroll 1
    for (int t = 0; t < RT; ++t) {
        // 2-deep X prefetch (full-step completion window)
        float4 xnA = {0,0,0,0}, xnB = {0,0,0,0};
        if (kc == 0) {
            const float* xnp = (t + 1 < RT) ? (xPtr + RN) : xPtr;
            xnA = *reinterpret_cast<const float4*>(xnp);
            xnB = *reinterpret_cast<const float4*>(xnp + 4);
        }

        // ---- phase A: own half (64 dot2), th from ownpk -- no partner dep ----
        float a0 = 0.f, a1 = 0.f, a2 = 0.f, a3 = 0.f;
        float a4 = 0.f, a5 = 0.f, a6 = 0.f, a7 = 0.f;
        {
            uint4 th0 = *reinterpret_cast<const uint4*>(&ownpk[kc * 8]);
            uint4 th1 = *reinterpret_cast<const uint4*>(&ownpk[kc * 8 + 4]);
            DOTA(0) DOTA(1) DOTA(2) DOTA(3) DOTA(4) DOTA(5) DOTA(6) DOTA(7)
        }

        // ---- wait for both parts of step t-1 (tid0 hot poll + barrier) ----
        if (tid == 0 && t > 0) {
            const unsigned tgt = 2u * (unsigned)t;
            while (__hip_atomic_load(gctr, __ATOMIC_RELAXED,
                                     __HIP_MEMORY_SCOPE_AGENT) < tgt) { }
        }
        __syncthreads();

        // ---- phase B: ONE partner band (4 float4 + 8 pkrtz + 64 dot2) ----
        {
            const float* p = srcB + hfp * 256 + kc * 16;
            float4 f0 = *reinterpret_cast<const float4*>(p);
            float4 f1 = *reinterpret_cast<const float4*>(p + 4);
            float4 f2 = *reinterpret_cast<const float4*>(p + 8);
            float4 f3 = *reinterpret_cast<const float4*>(p + 12);
            uint4 tb0 = make_uint4(pkrtz(f0.x, f0.y), pkrtz(f0.z, f0.w),
                                   pkrtz(f1.x, f1.y), pkrtz(f1.z, f1.w));
            uint4 tb1 = make_uint4(pkrtz(f2.x, f2.y), pkrtz(f2.z, f2.w),
                                   pkrtz(f3.x, f3.y), pkrtz(f3.z, f3.w));
            DOTBq(0) DOTBq(1) DOTBq(2) DOTBq(3) DOTBq(4) DOTBq(5) DOTBq(6) DOTBq(7)
        }

        // ---- 16-lane all-reduce in VALU (DPP) ----
        a0 = red16(a0); a1 = red16(a1); a2 = red16(a2); a3 = red16(a3);
        a4 = red16(a4); a5 = red16(a5); a6 = red16(a6); a7 = red16(a7);

        if (kc == 0) {
            hA.x = 0.9f * hA.x + 0.1f * (a0 + xvA.x);
            hA.y = 0.9f * hA.y + 0.1f * (a1 + xvA.y);
            hA.z = 0.9f * hA.z + 0.1f * (a2 + xvA.z);
            hA.w = 0.9f * hA.w + 0.1f * (a3 + xvA.w);
            hB.x = 0.9f * hB.x + 0.1f * (a4 + xvB.x);
            hB.y = 0.9f * hB.y + 0.1f * (a5 + xvB.y);
            hB.z = 0.9f * hB.z + 0.1f * (a6 + xvB.z);
            hB.w = 0.9f * hB.w + 0.1f * (a7 + xvB.w);
            float t0 = fast_tanh(hA.x), t1 = fast_tanh(hA.y);
            float t2 = fast_tanh(hA.z), t3 = fast_tanh(hA.w);
            float t4 = fast_tanh(hB.x), t5 = fast_tanh(hB.y);
            float t6 = fast_tanh(hB.z), t7 = fast_tanh(hB.w);
            *reinterpret_cast<float4*>(oPtr)     = make_float4(t0, t1, t2, t3);
            *reinterpret_cast<float4*>(oPtr + 4) = make_float4(t4, t5, t6, t7);
            *reinterpret_cast<uint4*>(&ownpk[rg * 4]) =
                make_uint4(pack2(t0, t1), pack2(t2, t3), pack2(t4, t5), pack2(t6, t7));
        }

        // ---- signal hoist: per-wave drain -> LDS arrival -> 8th wave fires ----
        asm volatile("s_waitcnt vmcnt(0)" ::: "memory");   // stores in XCD L2
        if ((tid & 63) == 0) {
            unsigned a = __hip_atomic_fetch_add(lctr, 1u, __ATOMIC_RELAXED,
                                                __HIP_MEMORY_SCOPE_WORKGROUP);
            if ((a & 7u) == 7u)
                __hip_atomic_fetch_add(gctr, 1u, __ATOMIC_RELAXED,
                                       __HIP_MEMORY_SCOPE_AGENT);
        }
        __syncthreads();   // ownpk coherence for next step's phase A
        xvA = xnA; xvB = xnB;

        srcB = (t == 0) ? oBase : (srcB + RN);
        xPtr += RN;
        oPtr += RN;
    }
}

// one-time: W -> f16 pairs. Wpk[p*16384 + hf*8192 + k*512 + tid] where k=r*2+j
// = W[p*256 + (tid>>4)*8 + r][hf*256 + (tid&15)*16 + j*8 .. +8)
__global__ void pack_w(const float* __restrict__ W, uint4* __restrict__ Wpk)
{
    int o = blockIdx.x * blockDim.x + threadIdx.x;
    if (o >= 32768) return;
    int p   = o >> 14;
    int hf  = (o >> 13) & 1;
    int k   = (o >> 9) & 15;
    int tid = o & 511;
    int r = k >> 1, j = k & 1;
    int row = p * 256 + (tid >> 4) * 8 + r;
    int col = hf * 256 + (tid & 15) * 16 + j * 8;
    const float* s = W + (size_t)row * RN + col;
    uint4 v;
    v.x = pack2(s[0], s[1]); v.y = pack2(s[2], s[3]);
    v.z = pack2(s[4], s[5]); v.w = pack2(s[6], s[7]);
    Wpk[o] = v;
}

// geometry epilogue: geo[b,t,:] = hidden[b,t,:] @ Gw^T + Gb ; one wave per (b,t)
__global__ void geom_kernel(const float* __restrict__ hid,
                            const float* __restrict__ Gw,
                            const float* __restrict__ Gb,
                            float* __restrict__ geo)
{
    const int wid  = (blockIdx.x * blockDim.x + threadIdx.x) >> 6;
    const int lane = threadIdx.x & 63;
    if (wid >= RB * RT) return;
    const float* rowp = hid + (size_t)wid * RN;
    float g0 = 0.f, g1 = 0.f;
    #pragma unroll
    for (int j = 0; j < 8; ++j) {
        float v = rowp[lane + 64 * j];
        g0 = fmaf(v, Gw[lane + 64 * j], g0);
        g1 = fmaf(v, Gw[RN + lane + 64 * j], g1);
    }
    #pragma unroll
    for (int m = 32; m >= 1; m >>= 1) {
        g0 += __shfl_xor(g0, m);
        g1 += __shfl_xor(g1, m);
    }
    if (lane == 0) {
        geo[(size_t)wid * 2]     = g0 + Gb[0];
        geo[(size_t)wid * 2 + 1] = g1 + Gb[1];
    }
}

// per-launch init (ws poisoned once, never re-poisoned -> re-init every call)
__global__ void init_misc(const float* __restrict__ h0,
                          float* __restrict__ tanh0,
                          unsigned* __restrict__ ctr,
                          unsigned* __restrict__ xcdctr)
{
    int i = blockIdx.x * blockDim.x + threadIdx.x;
    if (i < RN) tanh0[i] = tanhf(h0[i]);
    if (i < RB * 32) ctr[i] = 0u;
    if (i < 8) xcdctr[i] = 0u;
}

extern "C" void kernel_launch(void* const* d_in, const int* in_sizes, int n_in,
                              void* d_out, int out_size, void* d_ws, size_t ws_size,
                              hipStream_t stream)
{
    const float* h0 = (const float*)d_in[0];
    const float* X  = (const float*)d_in[1];
    const float* W  = (const float*)d_in[2];
    const float* Gw = (const float*)d_in[3];
    const float* Gb = (const float*)d_in[4];

    float* outH = (float*)d_out;
    float* geo  = outH + (size_t)RB * RT * RN;

    float*    tanh0  = (float*)d_ws;                  // 512 f32
    unsigned* ctr    = (unsigned*)d_ws + RN;          // 64*32 u32
    unsigned* xcdctr = ctr + RB * 32;                 // 8 u32
    uint4*    Wpk    = (uint4*)(((uintptr_t)(xcdctr + 8) + 63) & ~(uintptr_t)63);

    (void)hipFuncSetAttribute((const void*)rnn_step_kernel,
                              hipFuncAttributeMaxDynamicSharedMemorySize, SMEM_BYTES);

    pack_w<<<64, 512, 0, stream>>>(W, Wpk);
    init_misc<<<8, 512, 0, stream>>>(h0, tanh0, ctr, xcdctr);

    void* kargs[] = { (void*)&h0, (void*)&X, (void*)&Wpk, (void*)&tanh0,
                      (void*)&outH, (void*)&ctr, (void*)&xcdctr };
    (void)hipLaunchCooperativeKernel(rnn_step_kernel, dim3(256), dim3(512),
                                     kargs, SMEM_BYTES, stream);

    geom_kernel<<<(RB * RT * 64 + 255) / 256, 256, 0, stream>>>(outH, Gw, Gb, geo);
}